// Round 15
// baseline (158.475 us; speedup 1.0000x reference)
//
#include <hip/hip_runtime.h>

// Fused actor-critic forward for S=256,B=1024,D=64,H=128,A=8.
// R15: occupancy via the allocation model learned from R8/R14 spills:
// at launch_bounds(256,4) the arch-VGPR budget is 128 - max_AGPR(kernel).
// R14's gate halves (48 AGPR) left 80 arch < ~84 needed -> spill. Fix:
// gate GEMMs in FOUR 16-row quarters (ai/ag/ao = 24 AGPR) so kernel-wide
// max AGPR stays 32 (MLP acc[4][2]) -> arch budget 96 >= ~84 -> fits.
// Same MFMA count & 6-MFMA-per-a-frag intensity; gate weights re-read 4x
// from hot L2 (hidden by 24 MFMAs/quarter + 4 waves/SIMD).
// Canaries: VGPR_Count 80-96 & WRITE_SIZE ~20MB = no spill.
// Base = R12: weights never in LDS (frag-ordered bf16 images in ws),
// double-buffered activations, packed-f32 gate math, setprio on MFMA.

#define NROWS (256 * 1024)
#define HID 128
#define ACTD 8

// ws layout (bytes) — all weight images frag-ordered:
// chunk dst = (((ftile*KC + kc)*4 + ks)*16 + r)*16 ; lane addr = base +
// ((ftile*KC+kc)<<10) + ((lane>>4)<<8) + ((lane&15)<<4) ; ftile = 16 feats
#define W1_OFF 0                  // [128f][64K]  KC=2, 16KB
#define W2_OFF 16384              // [128][128]   KC=4, 32KB
#define WI_OFF 49152              // wih rows 0..127
#define WG_OFF 81920              // wih rows 256..383
#define WO_OFF 114688             // wih rows 384..511
#define PSTR 147456               // per-path stride
#define HEAD_OFF (2 * PSTR)       // actor [mw;lw] 4KB, critic [vw;0] 4KB
#define GB_OFF (HEAD_OFF + 8192)  // prescaled gate biases, 384 f32 per path

#define NEG_L (-1.4426950408889634f)
#define TWO_L (2.8853900817779268f)

typedef __attribute__((ext_vector_type(8))) short s16x8;
typedef __attribute__((ext_vector_type(4))) float fx4;
typedef __attribute__((ext_vector_type(2))) float fx2;
typedef __attribute__((ext_vector_type(2))) unsigned int u32x2;
typedef __attribute__((ext_vector_type(4))) unsigned int u32x4;

__device__ __forceinline__ unsigned int cvtpk(float lo, float hi) {
  unsigned int r;
  asm("v_cvt_pk_bf16_f32 %0, %1, %2" : "=v"(r) : "v"(lo), "v"(hi));
  return r;
}
__device__ __forceinline__ float ex2(float x) {
  return __builtin_amdgcn_exp2f(x);
}
__device__ __forceinline__ float frcp(float x) {
  return __builtin_amdgcn_rcpf(x);
}
__device__ __forceinline__ fx2 mk2(float a, float b) {
  fx2 v;
  v[0] = a;
  v[1] = b;
  return v;
}

// 8 bf16 from swizzled LDS tile: row-major 2^rowsh B/row, chunk XOR (row&7)<<4
__device__ __forceinline__ s16x8 frag_ld(const unsigned short* base, int row,
                                         int kbyte, int rowsh) {
  int byte = (row << rowsh) + (kbyte ^ ((row & 7) << 4));
  return *(const s16x8*)((const char*)base + byte);
}

struct wpair {
  s16x8 w0, w1;
};
// load one (kc) weight-fragment pair (2 x 16-feat tiles) from frag-ordered img
template <int KC>
__device__ __forceinline__ wpair wload(const char* __restrict__ wimg, int wv,
                                       int kc, int woff) {
  wpair p;
  p.w0 = *(const s16x8*)(wimg + (((wv * 2 + 0) * KC + kc) << 10) + woff);
  p.w1 = *(const s16x8*)(wimg + (((wv * 2 + 1) * KC + kc) << 10) + woff);
  return p;
}

// one kc step: 4 row-tiles of MFMA against a prefetched weight pair
template <int ASH>
__device__ __forceinline__ void gemm_kc(const wpair& p,
                                        const unsigned short* at, int kbyte,
                                        int l15, fx4 acc[4][2]) {
#pragma unroll
  for (int jt = 0; jt < 4; ++jt) {
    s16x8 a = frag_ld(at, jt * 16 + l15, kbyte, ASH);
    acc[jt][0] = __builtin_amdgcn_mfma_f32_16x16x32_bf16(p.w0, a, acc[jt][0], 0, 0, 0);
    acc[jt][1] = __builtin_amdgcn_mfma_f32_16x16x32_bf16(p.w1, a, acc[jt][1], 0, 0, 0);
  }
}

__device__ __forceinline__ void bacc(fx4 acc[4][2], const float* __restrict__ b,
                                     int fb, int g4) {
#pragma unroll
  for (int it = 0; it < 2; ++it) {
    fx4 bv = *(const fx4*)(b + fb + it * 16 + g4);
#pragma unroll
    for (int jt = 0; jt < 4; ++jt) acc[jt][it] = bv;
  }
}

// acc (bias already in) -> relu -> bf16 -> swizzled buf [64][128f] 256B rows
__device__ __forceinline__ void epi_relu(fx4 acc[4][2], unsigned short* obuf,
                                         int fb, int lane) {
  const int g4 = (lane >> 4) << 2;
  const int l15 = lane & 15;
  char* ob = (char*)obuf;
#pragma unroll
  for (int it = 0; it < 2; ++it) {
    int n0 = fb + it * 16 + g4;
#pragma unroll
    for (int jt = 0; jt < 4; ++jt) {
      fx4 v = acc[jt][it];
#pragma unroll
      for (int r = 0; r < 4; ++r) v[r] = fmaxf(v[r], 0.0f);
      u32x2 u;
      u[0] = cvtpk(v[0], v[1]);
      u[1] = cvtpk(v[2], v[3]);
      int m = jt * 16 + l15;
      *(u32x2*)(ob + (m << 8) + ((n0 * 2) ^ ((m & 7) << 4))) = u;
    }
  }
}

// ---------------- prep: weights -> bf16 frag-ordered images ----------------
__global__ void prep_weights(const float* __restrict__ aw1,
                             const float* __restrict__ aw2,
                             const float* __restrict__ awih,
                             const float* __restrict__ cw1,
                             const float* __restrict__ cw2,
                             const float* __restrict__ cwih,
                             const float* __restrict__ mw,
                             const float* __restrict__ lw,
                             const float* __restrict__ vw,
                             const float* __restrict__ abih,
                             const float* __restrict__ abhh,
                             const float* __restrict__ cbih,
                             const float* __restrict__ cbhh,
                             char* __restrict__ ws) {
  int y = blockIdx.y;
  int idx = blockIdx.x * 256 + threadIdx.x;
  if (y >= 12) {  // prescaled gate biases: [pgi(128); pgg(128); pgo(128)]
    if (idx < 384) {
      float* dst = (float*)(ws + GB_OFF + (size_t)(y - 12) * 1536);
      const float* b0 = (y == 12) ? abih : cbih;
      const float* b1 = (y == 12) ? abhh : cbhh;
      int sect = idx >> 7, f = idx & 127;
      int srow = (sect == 0) ? f : (sect == 1) ? 256 + f : 384 + f;
      float scale = (sect == 1) ? TWO_L : NEG_L;
      dst[idx] = scale * (b0[srow] + b1[srow]);
    }
    return;
  }
  if (y >= 10) {  // head images: 16 rows x 128 K, frag-ordered (ftile=0)
    if (idx >= 256) return;
    int row = idx >> 4, c16 = idx & 15, kc = c16 >> 2, ks = c16 & 3;
    fx4 v0 = {0.f, 0.f, 0.f, 0.f}, v1 = v0;
    if (y == 10) {
      const float* src = (row < 8) ? (mw + (size_t)row * HID + c16 * 8)
                                   : (lw + (size_t)(row - 8) * HID + c16 * 8);
      v0 = ((const fx4*)src)[0];
      v1 = ((const fx4*)src)[1];
    } else if (row == 0) {
      const float* src = vw + c16 * 8;
      v0 = ((const fx4*)src)[0];
      v1 = ((const fx4*)src)[1];
    }
    u32x4 u;
    u[0] = cvtpk(v0[0], v0[1]);
    u[1] = cvtpk(v0[2], v0[3]);
    u[2] = cvtpk(v1[0], v1[1]);
    u[3] = cvtpk(v1[2], v1[3]);
    int dst = ((kc * 4 + ks) * 16 + row) * 16;
    *(u32x4*)(ws + HEAD_OFF + (size_t)(y - 10) * 4096 + dst) = u;
    return;
  }
  const float* src;
  int nch, ksh, KC, off;
  switch (y) {
    case 0:  src = aw1;              nch = 1024; ksh = 3; KC = 2; off = W1_OFF;        break;
    case 1:  src = aw2;              nch = 2048; ksh = 4; KC = 4; off = W2_OFF;        break;
    case 2:  src = awih;             nch = 2048; ksh = 4; KC = 4; off = WI_OFF;        break;
    case 3:  src = awih + 256 * HID; nch = 2048; ksh = 4; KC = 4; off = WG_OFF;        break;
    case 4:  src = awih + 384 * HID; nch = 2048; ksh = 4; KC = 4; off = WO_OFF;        break;
    case 5:  src = cw1;              nch = 1024; ksh = 3; KC = 2; off = PSTR + W1_OFF; break;
    case 6:  src = cw2;              nch = 2048; ksh = 4; KC = 4; off = PSTR + W2_OFF; break;
    case 7:  src = cwih;             nch = 2048; ksh = 4; KC = 4; off = PSTR + WI_OFF; break;
    case 8:  src = cwih + 256 * HID; nch = 2048; ksh = 4; KC = 4; off = PSTR + WG_OFF; break;
    default: src = cwih + 384 * HID; nch = 2048; ksh = 4; KC = 4; off = PSTR + WO_OFF; break;
  }
  if (idx >= nch) return;
  int row = idx >> ksh;
  int c16 = idx & ((1 << ksh) - 1);
  int b2 = row >> 4, r = row & 15, kc = c16 >> 2, ks = c16 & 3;
  const fx4* gp = (const fx4*)(src + (size_t)idx * 8);
  fx4 v0 = gp[0], v1 = gp[1];
  u32x4 u;
  u[0] = cvtpk(v0[0], v0[1]);
  u[1] = cvtpk(v0[2], v0[3]);
  u[2] = cvtpk(v1[0], v1[1]);
  u[3] = cvtpk(v1[2], v1[3]);
  int dst = (((b2 * KC + kc) * 4 + ks) * 16 + r) * 16;
  *(u32x4*)(ws + off + dst) = u;
}

// ---------------- main fused kernel: one path x 64 rows per block ----------
__global__ __launch_bounds__(256, 4) void fused_ac(
    const float* __restrict__ state, const float* __restrict__ ab1,
    const float* __restrict__ ab2, const float* __restrict__ cb1,
    const float* __restrict__ cb2, const float* __restrict__ mb,
    const float* __restrict__ lb, const float* __restrict__ vb,
    const char* __restrict__ ws, float* __restrict__ outp) {
  __shared__ __align__(16) unsigned short abuf[8192];  // 16KB: X -> H2
  __shared__ __align__(16) unsigned short hbuf[8192];  // 16KB: H1 -> h

  const int tid = threadIdx.x;
  const int lane = tid & 63;
  const int wv = tid >> 6;
  const int l15 = lane & 15;
  const int g4 = (lane >> 4) << 2;
  const int kb0 = (lane >> 4) << 4;
  const int woff = ((lane >> 4) << 8) + (l15 << 4);
  const int fb = wv << 5;  // feature band base
  const int path = blockIdx.x >> 12;
  const int rbase = (blockIdx.x & 4095) << 6;  // 64 rows per block

  const char* wsp = ws + (size_t)path * PSTR;
  const float* b1 = path ? cb1 : ab1;
  const float* b2 = path ? cb2 : ab2;
  const float* gb = (const float*)(ws + GB_OFF + (size_t)path * 1536);
  const char* himg = ws + HEAD_OFF + (size_t)path * 4096;

  float* meanp = outp;
  float* stdp = outp + (size_t)NROWS * ACTD;
  float* valp = outp + (size_t)NROWS * ACTD * 2;

  // prefetch ALL of W1 (KC=2) while staging X
  wpair w1a = wload<2>(wsp + W1_OFF, wv, 0, woff);
  wpair w1b = wload<2>(wsp + W1_OFF, wv, 1, woff);

  // stage X [64][64] f32 -> bf16 swizzled (128B rows) into abuf
  {
    const float* xg = state + (size_t)rbase * 64;
    char* ab = (char*)abuf;
#pragma unroll
    for (int i = 0; i < 2; ++i) {
      int idx = tid + i * 256;
      int r = idx >> 3, c = idx & 7;
      const fx4* gp = (const fx4*)(xg + idx * 8);
      fx4 v0 = gp[0], v1 = gp[1];
      u32x4 u;
      u[0] = cvtpk(v0[0], v0[1]);
      u[1] = cvtpk(v0[2], v0[3]);
      u[2] = cvtpk(v1[0], v1[1]);
      u[3] = cvtpk(v1[2], v1[3]);
      *(u32x4*)(ab + r * 128 + ((c << 4) ^ ((r & 7) << 4))) = u;
    }
  }
  __syncthreads();  // (1) X visible

  fx4 acc[4][2];
  bacc(acc, b1, fb, g4);
  __builtin_amdgcn_s_setprio(1);
  gemm_kc<7>(w1a, abuf, 0 + kb0, l15, acc);   // H1 = X*W1^T + b1
  gemm_kc<7>(w1b, abuf, 64 + kb0, l15, acc);
  __builtin_amdgcn_s_setprio(0);
  // prefetch W2 kc0,kc1; epilogue H1 -> hbuf (no WAR: different buffer)
  wpair w2a = wload<4>(wsp + W2_OFF, wv, 0, woff);
  wpair w2b = wload<4>(wsp + W2_OFF, wv, 1, woff);
  epi_relu(acc, hbuf, fb, lane);
  __syncthreads();  // (2) H1 visible

  bacc(acc, b2, fb, g4);
  __builtin_amdgcn_s_setprio(1);
  gemm_kc<8>(w2a, hbuf, 0 + kb0, l15, acc);   // H2 = H1*W2^T + b2
  gemm_kc<8>(w2b, hbuf, 64 + kb0, l15, acc);
  {
    wpair p = wload<4>(wsp + W2_OFF, wv, 2, woff);
    gemm_kc<8>(p, hbuf, 128 + kb0, l15, acc);
  }
  {
    wpair p = wload<4>(wsp + W2_OFF, wv, 3, woff);
    gemm_kc<8>(p, hbuf, 192 + kb0, l15, acc);
  }
  __builtin_amdgcn_s_setprio(0);
  epi_relu(acc, abuf, fb, lane);
  __syncthreads();  // (3) H2 visible

  // ---- FUSED gate GEMMs in FOUR 16-row quarters (24 AGPR, max stays 32) ----
#pragma unroll
  for (int q = 0; q < 4; ++q) {
    const int ro = q << 4;  // row offset
    fx4 ai[2], ag[2], ao[2];
#pragma unroll
    for (int it = 0; it < 2; ++it) {
      ai[it] = fx4{0.f, 0.f, 0.f, 0.f};
      ag[it] = fx4{0.f, 0.f, 0.f, 0.f};
      ao[it] = fx4{0.f, 0.f, 0.f, 0.f};
    }
    __builtin_amdgcn_s_setprio(1);
#pragma unroll
    for (int kc = 0; kc < 4; ++kc) {
      wpair pi = wload<4>(wsp + WI_OFF, wv, kc, woff);
      wpair pg = wload<4>(wsp + WG_OFF, wv, kc, woff);
      wpair po = wload<4>(wsp + WO_OFF, wv, kc, woff);
      s16x8 a = frag_ld(abuf, ro + l15, kc * 64 + kb0, 8);
      ai[0] = __builtin_amdgcn_mfma_f32_16x16x32_bf16(pi.w0, a, ai[0], 0, 0, 0);
      ai[1] = __builtin_amdgcn_mfma_f32_16x16x32_bf16(pi.w1, a, ai[1], 0, 0, 0);
      ag[0] = __builtin_amdgcn_mfma_f32_16x16x32_bf16(pg.w0, a, ag[0], 0, 0, 0);
      ag[1] = __builtin_amdgcn_mfma_f32_16x16x32_bf16(pg.w1, a, ag[1], 0, 0, 0);
      ao[0] = __builtin_amdgcn_mfma_f32_16x16x32_bf16(po.w0, a, ao[0], 0, 0, 0);
      ao[1] = __builtin_amdgcn_mfma_f32_16x16x32_bf16(po.w1, a, ao[1], 0, 0, 0);
    }
    __builtin_amdgcn_s_setprio(0);
    // gate math for rows ro..ro+15, packed f32 pairs: h -> hbuf
    char* ob = (char*)hbuf;
#pragma unroll
    for (int it = 0; it < 2; ++it) {
      fx4 pvi = *(const fx4*)(gb + fb + it * 16 + g4);
      fx4 pvg = *(const fx4*)(gb + 128 + fb + it * 16 + g4);
      fx4 pvo = *(const fx4*)(gb + 256 + fb + it * 16 + g4);
      int n0 = fb + it * 16 + g4;
      u32x2 u;
#pragma unroll
      for (int p = 0; p < 2; ++p) {
        const int r0 = 2 * p, r1 = 2 * p + 1;
        fx2 vi = mk2(ai[it][r0], ai[it][r1]);
        fx2 vg = mk2(ag[it][r0], ag[it][r1]);
        fx2 vo = mk2(ao[it][r0], ao[it][r1]);
        fx2 ti = vi * NEG_L + mk2(pvi[r0], pvi[r1]);  // pk_fma
        fx2 tg = vg * TWO_L + mk2(pvg[r0], pvg[r1]);
        fx2 to = vo * NEG_L + mk2(pvo[r0], pvo[r1]);
        fx2 Ei = mk2(ex2(ti[0]), ex2(ti[1]));
        fx2 Eg = mk2(ex2(tg[0]), ex2(tg[1]));
        fx2 Eo = mk2(ex2(to[0]), ex2(to[1]));
        fx2 d1 = (Eg + 1.0f) * (Ei + 1.0f);
        fx2 r1v = mk2(frcp(d1[0]), frcp(d1[1]));
        fx2 c = (Eg - 1.0f) * r1v;
        fx2 ea = c * TWO_L;
        fx2 Ec = mk2(ex2(ea[0]), ex2(ea[1]));
        fx2 d2 = (Ec + 1.0f) * (Eo + 1.0f);
        fx2 r2v = mk2(frcp(d2[0]), frcp(d2[1]));
        fx2 h2 = (Ec - 1.0f) * r2v;
        u[p] = cvtpk(h2[0], h2[1]);
      }
      int m = ro + l15;
      *(u32x2*)(ob + (m << 8) + ((n0 * 2) ^ ((m & 7) << 4))) = u;
    }
  }
  // prefetch head-weight fragments
  s16x8 hw0 = *(const s16x8*)(himg + (0 << 10) + woff);
  s16x8 hw1 = *(const s16x8*)(himg + (1 << 10) + woff);
  s16x8 hw2 = *(const s16x8*)(himg + (2 << 10) + woff);
  s16x8 hw3 = *(const s16x8*)(himg + (3 << 10) + woff);
  __syncthreads();  // (4) h visible

  // head GEMM: wave wv -> rows wv*16..+15
  fx4 ha = fx4{0.f, 0.f, 0.f, 0.f};
  __builtin_amdgcn_s_setprio(1);
  ha = __builtin_amdgcn_mfma_f32_16x16x32_bf16(
      hw0, frag_ld(hbuf, (wv << 4) + l15, 0 + kb0, 8), ha, 0, 0, 0);
  ha = __builtin_amdgcn_mfma_f32_16x16x32_bf16(
      hw1, frag_ld(hbuf, (wv << 4) + l15, 64 + kb0, 8), ha, 0, 0, 0);
  ha = __builtin_amdgcn_mfma_f32_16x16x32_bf16(
      hw2, frag_ld(hbuf, (wv << 4) + l15, 128 + kb0, 8), ha, 0, 0, 0);
  ha = __builtin_amdgcn_mfma_f32_16x16x32_bf16(
      hw3, frag_ld(hbuf, (wv << 4) + l15, 192 + kb0, 8), ha, 0, 0, 0);
  __builtin_amdgcn_s_setprio(0);

  int m = rbase + (wv << 4) + l15;
  if (path == 0) {
    if (g4 < 8) {
      fx4 v = ha + *(const fx4*)(mb + g4);
      *(fx4*)(meanp + (size_t)m * ACTD + g4) = v;
    } else {
      fx4 v;
#pragma unroll
      for (int r = 0; r < 4; ++r) v[r] = __expf(ha[r] + lb[g4 - 8 + r]);
      *(fx4*)(stdp + (size_t)m * ACTD + (g4 - 8)) = v;
    }
  } else if (g4 == 0) {
    valp[m] = ha[0] + vb[0];
  }
}

extern "C" void kernel_launch(void* const* d_in, const int* in_sizes, int n_in,
                              void* d_out, int out_size, void* d_ws,
                              size_t ws_size, hipStream_t stream) {
  (void)in_sizes; (void)n_in; (void)ws_size; (void)out_size;
  const float* state = (const float*)d_in[0];
  const float* aw1 = (const float*)d_in[1];
  const float* ab1 = (const float*)d_in[2];
  const float* aw2 = (const float*)d_in[3];
  const float* ab2 = (const float*)d_in[4];
  const float* cw1 = (const float*)d_in[5];
  const float* cb1 = (const float*)d_in[6];
  const float* cw2 = (const float*)d_in[7];
  const float* cb2 = (const float*)d_in[8];
  const float* awih = (const float*)d_in[9];
  // d_in[10] = a_whh (unused: zero-state LSTM)
  const float* abih = (const float*)d_in[11];
  const float* abhh = (const float*)d_in[12];
  const float* cwih = (const float*)d_in[13];
  // d_in[14] = c_whh (unused)
  const float* cbih = (const float*)d_in[15];
  const float* cbhh = (const float*)d_in[16];
  const float* mw = (const float*)d_in[17];
  const float* mb = (const float*)d_in[18];
  const float* lw = (const float*)d_in[19];
  const float* lb = (const float*)d_in[20];
  const float* vw = (const float*)d_in[21];
  const float* vb = (const float*)d_in[22];
  char* ws = (char*)d_ws;

  prep_weights<<<dim3(8, 14), 256, 0, stream>>>(
      aw1, aw2, awih, cw1, cw2, cwih, mw, lw, vw, abih, abhh, cbih, cbhh, ws);
  fused_ac<<<8192, 256, 0, stream>>>(state, ab1, ab2, cb1, cb2, mb, lb, vb, ws,
                                     (float*)d_out);
}

// Round 16
// 116.286 us; speedup vs baseline: 1.3628x; 1.3628x over previous
//
#include <hip/hip_runtime.h>

// Fused actor-critic forward for S=256,B=1024,D=64,H=128,A=8.
// R16 = R12 verbatim (session best: 116.65us). The occupancy/intensity trade
// was probed on three axes (R10 feat-split, R14 row-halves, R15 row-quarters)
// and every point loses to this configuration: 4 waves x 32 feats, 3
// waves/SIMD (96-AGPR fused-gate phase + ~84 arch VGPR on the unified file),
// MFMA:load 4:1 in the gate phase, VALU floor ~64us chip-wide.
// Structure: weights never touch LDS (frag-ordered bf16 images in ws),
// double-buffered activations (abuf: X->H2, hbuf: H1->h), cross-barrier
// weight prefetch, fused i/g/o gate GEMMs, packed-f32 gate math
// (4 exp2 + 2 rcp / elem, prescaled biases), s_setprio around MFMA.

#define NROWS (256 * 1024)
#define HID 128
#define ACTD 8

// ws layout (bytes) — all weight images frag-ordered:
// chunk dst = (((ftile*KC + kc)*4 + ks)*16 + r)*16 ; lane addr = base +
// ((ftile*KC+kc)<<10) + ((lane>>4)<<8) + ((lane&15)<<4) ; ftile = 16 feats
#define W1_OFF 0                  // [128f][64K]  KC=2, 16KB
#define W2_OFF 16384              // [128][128]   KC=4, 32KB
#define WI_OFF 49152              // wih rows 0..127
#define WG_OFF 81920              // wih rows 256..383
#define WO_OFF 114688             // wih rows 384..511
#define PSTR 147456               // per-path stride
#define HEAD_OFF (2 * PSTR)       // actor [mw;lw] 4KB, critic [vw;0] 4KB
#define GB_OFF (HEAD_OFF + 8192)  // prescaled gate biases, 384 f32 per path

#define NEG_L (-1.4426950408889634f)
#define TWO_L (2.8853900817779268f)

typedef __attribute__((ext_vector_type(8))) short s16x8;
typedef __attribute__((ext_vector_type(4))) float fx4;
typedef __attribute__((ext_vector_type(2))) float fx2;
typedef __attribute__((ext_vector_type(2))) unsigned int u32x2;
typedef __attribute__((ext_vector_type(4))) unsigned int u32x4;

__device__ __forceinline__ unsigned int cvtpk(float lo, float hi) {
  unsigned int r;
  asm("v_cvt_pk_bf16_f32 %0, %1, %2" : "=v"(r) : "v"(lo), "v"(hi));
  return r;
}
__device__ __forceinline__ float ex2(float x) {
  return __builtin_amdgcn_exp2f(x);
}
__device__ __forceinline__ float frcp(float x) {
  return __builtin_amdgcn_rcpf(x);
}
__device__ __forceinline__ fx2 mk2(float a, float b) {
  fx2 v;
  v[0] = a;
  v[1] = b;
  return v;
}

// 8 bf16 from swizzled LDS tile: row-major 2^rowsh B/row, chunk XOR (row&7)<<4
__device__ __forceinline__ s16x8 frag_ld(const unsigned short* base, int row,
                                         int kbyte, int rowsh) {
  int byte = (row << rowsh) + (kbyte ^ ((row & 7) << 4));
  return *(const s16x8*)((const char*)base + byte);
}

struct wpair {
  s16x8 w0, w1;
};
// load one (kc) weight-fragment pair (2 x 16-feat tiles) from frag-ordered img
template <int KC>
__device__ __forceinline__ wpair wload(const char* __restrict__ wimg, int wv,
                                       int kc, int woff) {
  wpair p;
  p.w0 = *(const s16x8*)(wimg + (((wv * 2 + 0) * KC + kc) << 10) + woff);
  p.w1 = *(const s16x8*)(wimg + (((wv * 2 + 1) * KC + kc) << 10) + woff);
  return p;
}

// one kc step: 4 row-tiles of MFMA against a prefetched weight pair
template <int ASH>
__device__ __forceinline__ void gemm_kc(const wpair& p,
                                        const unsigned short* at, int kbyte,
                                        int l15, fx4 acc[4][2]) {
#pragma unroll
  for (int jt = 0; jt < 4; ++jt) {
    s16x8 a = frag_ld(at, jt * 16 + l15, kbyte, ASH);
    acc[jt][0] = __builtin_amdgcn_mfma_f32_16x16x32_bf16(p.w0, a, acc[jt][0], 0, 0, 0);
    acc[jt][1] = __builtin_amdgcn_mfma_f32_16x16x32_bf16(p.w1, a, acc[jt][1], 0, 0, 0);
  }
}

__device__ __forceinline__ void zacc(fx4 acc[4][2]) {
#pragma unroll
  for (int j = 0; j < 4; ++j)
#pragma unroll
    for (int i = 0; i < 2; ++i) acc[j][i] = fx4{0.f, 0.f, 0.f, 0.f};
}
__device__ __forceinline__ void bacc(fx4 acc[4][2], const float* __restrict__ b,
                                     int fb, int g4) {
#pragma unroll
  for (int it = 0; it < 2; ++it) {
    fx4 bv = *(const fx4*)(b + fb + it * 16 + g4);
#pragma unroll
    for (int jt = 0; jt < 4; ++jt) acc[jt][it] = bv;
  }
}

// acc (bias already in) -> relu -> bf16 -> swizzled buf [64][128f] 256B rows
__device__ __forceinline__ void epi_relu(fx4 acc[4][2], unsigned short* obuf,
                                         int fb, int lane) {
  const int g4 = (lane >> 4) << 2;
  const int l15 = lane & 15;
  char* ob = (char*)obuf;
#pragma unroll
  for (int it = 0; it < 2; ++it) {
    int n0 = fb + it * 16 + g4;
#pragma unroll
    for (int jt = 0; jt < 4; ++jt) {
      fx4 v = acc[jt][it];
#pragma unroll
      for (int r = 0; r < 4; ++r) v[r] = fmaxf(v[r], 0.0f);
      u32x2 u;
      u[0] = cvtpk(v[0], v[1]);
      u[1] = cvtpk(v[2], v[3]);
      int m = jt * 16 + l15;
      *(u32x2*)(ob + (m << 8) + ((n0 * 2) ^ ((m & 7) << 4))) = u;
    }
  }
}

// ---------------- prep: weights -> bf16 frag-ordered images ----------------
__global__ void prep_weights(const float* __restrict__ aw1,
                             const float* __restrict__ aw2,
                             const float* __restrict__ awih,
                             const float* __restrict__ cw1,
                             const float* __restrict__ cw2,
                             const float* __restrict__ cwih,
                             const float* __restrict__ mw,
                             const float* __restrict__ lw,
                             const float* __restrict__ vw,
                             const float* __restrict__ abih,
                             const float* __restrict__ abhh,
                             const float* __restrict__ cbih,
                             const float* __restrict__ cbhh,
                             char* __restrict__ ws) {
  int y = blockIdx.y;
  int idx = blockIdx.x * 256 + threadIdx.x;
  if (y >= 12) {  // prescaled gate biases: [pgi(128); pgg(128); pgo(128)]
    if (idx < 384) {
      float* dst = (float*)(ws + GB_OFF + (size_t)(y - 12) * 1536);
      const float* b0 = (y == 12) ? abih : cbih;
      const float* b1 = (y == 12) ? abhh : cbhh;
      int sect = idx >> 7, f = idx & 127;
      int srow = (sect == 0) ? f : (sect == 1) ? 256 + f : 384 + f;
      float scale = (sect == 1) ? TWO_L : NEG_L;
      dst[idx] = scale * (b0[srow] + b1[srow]);
    }
    return;
  }
  if (y >= 10) {  // head images: 16 rows x 128 K, frag-ordered (ftile=0)
    if (idx >= 256) return;
    int row = idx >> 4, c16 = idx & 15, kc = c16 >> 2, ks = c16 & 3;
    fx4 v0 = {0.f, 0.f, 0.f, 0.f}, v1 = v0;
    if (y == 10) {
      const float* src = (row < 8) ? (mw + (size_t)row * HID + c16 * 8)
                                   : (lw + (size_t)(row - 8) * HID + c16 * 8);
      v0 = ((const fx4*)src)[0];
      v1 = ((const fx4*)src)[1];
    } else if (row == 0) {
      const float* src = vw + c16 * 8;
      v0 = ((const fx4*)src)[0];
      v1 = ((const fx4*)src)[1];
    }
    u32x4 u;
    u[0] = cvtpk(v0[0], v0[1]);
    u[1] = cvtpk(v0[2], v0[3]);
    u[2] = cvtpk(v1[0], v1[1]);
    u[3] = cvtpk(v1[2], v1[3]);
    int dst = ((kc * 4 + ks) * 16 + row) * 16;
    *(u32x4*)(ws + HEAD_OFF + (size_t)(y - 10) * 4096 + dst) = u;
    return;
  }
  const float* src;
  int nch, ksh, KC, off;
  switch (y) {
    case 0:  src = aw1;              nch = 1024; ksh = 3; KC = 2; off = W1_OFF;        break;
    case 1:  src = aw2;              nch = 2048; ksh = 4; KC = 4; off = W2_OFF;        break;
    case 2:  src = awih;             nch = 2048; ksh = 4; KC = 4; off = WI_OFF;        break;
    case 3:  src = awih + 256 * HID; nch = 2048; ksh = 4; KC = 4; off = WG_OFF;        break;
    case 4:  src = awih + 384 * HID; nch = 2048; ksh = 4; KC = 4; off = WO_OFF;        break;
    case 5:  src = cw1;              nch = 1024; ksh = 3; KC = 2; off = PSTR + W1_OFF; break;
    case 6:  src = cw2;              nch = 2048; ksh = 4; KC = 4; off = PSTR + W2_OFF; break;
    case 7:  src = cwih;             nch = 2048; ksh = 4; KC = 4; off = PSTR + WI_OFF; break;
    case 8:  src = cwih + 256 * HID; nch = 2048; ksh = 4; KC = 4; off = PSTR + WG_OFF; break;
    default: src = cwih + 384 * HID; nch = 2048; ksh = 4; KC = 4; off = PSTR + WO_OFF; break;
  }
  if (idx >= nch) return;
  int row = idx >> ksh;
  int c16 = idx & ((1 << ksh) - 1);
  int b2 = row >> 4, r = row & 15, kc = c16 >> 2, ks = c16 & 3;
  const fx4* gp = (const fx4*)(src + (size_t)idx * 8);
  fx4 v0 = gp[0], v1 = gp[1];
  u32x4 u;
  u[0] = cvtpk(v0[0], v0[1]);
  u[1] = cvtpk(v0[2], v0[3]);
  u[2] = cvtpk(v1[0], v1[1]);
  u[3] = cvtpk(v1[2], v1[3]);
  int dst = (((b2 * KC + kc) * 4 + ks) * 16 + r) * 16;
  *(u32x4*)(ws + off + dst) = u;
}

// ---------------- main fused kernel: one path x 64 rows per block ----------
__global__ __launch_bounds__(256, 3) void fused_ac(
    const float* __restrict__ state, const float* __restrict__ ab1,
    const float* __restrict__ ab2, const float* __restrict__ cb1,
    const float* __restrict__ cb2, const float* __restrict__ mb,
    const float* __restrict__ lb, const float* __restrict__ vb,
    const char* __restrict__ ws, float* __restrict__ outp) {
  __shared__ __align__(16) unsigned short abuf[8192];  // 16KB: X -> H2
  __shared__ __align__(16) unsigned short hbuf[8192];  // 16KB: H1 -> h

  const int tid = threadIdx.x;
  const int lane = tid & 63;
  const int wv = tid >> 6;
  const int l15 = lane & 15;
  const int g4 = (lane >> 4) << 2;
  const int kb0 = (lane >> 4) << 4;
  const int woff = ((lane >> 4) << 8) + (l15 << 4);
  const int fb = wv << 5;  // feature band base
  const int path = blockIdx.x >> 12;
  const int rbase = (blockIdx.x & 4095) << 6;  // 64 rows per block

  const char* wsp = ws + (size_t)path * PSTR;
  const float* b1 = path ? cb1 : ab1;
  const float* b2 = path ? cb2 : ab2;
  const float* gb = (const float*)(ws + GB_OFF + (size_t)path * 1536);
  const char* himg = ws + HEAD_OFF + (size_t)path * 4096;

  float* meanp = outp;
  float* stdp = outp + (size_t)NROWS * ACTD;
  float* valp = outp + (size_t)NROWS * ACTD * 2;

  // prefetch ALL of W1 (KC=2) while staging X
  wpair w1a = wload<2>(wsp + W1_OFF, wv, 0, woff);
  wpair w1b = wload<2>(wsp + W1_OFF, wv, 1, woff);

  // stage X [64][64] f32 -> bf16 swizzled (128B rows) into abuf
  {
    const float* xg = state + (size_t)rbase * 64;
    char* ab = (char*)abuf;
#pragma unroll
    for (int i = 0; i < 2; ++i) {
      int idx = tid + i * 256;
      int r = idx >> 3, c = idx & 7;
      const fx4* gp = (const fx4*)(xg + idx * 8);
      fx4 v0 = gp[0], v1 = gp[1];
      u32x4 u;
      u[0] = cvtpk(v0[0], v0[1]);
      u[1] = cvtpk(v0[2], v0[3]);
      u[2] = cvtpk(v1[0], v1[1]);
      u[3] = cvtpk(v1[2], v1[3]);
      *(u32x4*)(ab + r * 128 + ((c << 4) ^ ((r & 7) << 4))) = u;
    }
  }
  __syncthreads();  // (1) X visible

  fx4 acc[4][2];
  bacc(acc, b1, fb, g4);
  __builtin_amdgcn_s_setprio(1);
  gemm_kc<7>(w1a, abuf, 0 + kb0, l15, acc);   // H1 = X*W1^T + b1
  gemm_kc<7>(w1b, abuf, 64 + kb0, l15, acc);
  __builtin_amdgcn_s_setprio(0);
  // prefetch W2 kc0,kc1; epilogue H1 -> hbuf (no WAR: different buffer)
  wpair w2a = wload<4>(wsp + W2_OFF, wv, 0, woff);
  wpair w2b = wload<4>(wsp + W2_OFF, wv, 1, woff);
  epi_relu(acc, hbuf, fb, lane);
  __syncthreads();  // (2) H1 visible

  bacc(acc, b2, fb, g4);
  __builtin_amdgcn_s_setprio(1);
  gemm_kc<8>(w2a, hbuf, 0 + kb0, l15, acc);   // H2 = H1*W2^T + b2
  gemm_kc<8>(w2b, hbuf, 64 + kb0, l15, acc);
  {
    wpair p = wload<4>(wsp + W2_OFF, wv, 2, woff);
    gemm_kc<8>(p, hbuf, 128 + kb0, l15, acc);
  }
  {
    wpair p = wload<4>(wsp + W2_OFF, wv, 3, woff);
    gemm_kc<8>(p, hbuf, 192 + kb0, l15, acc);
  }
  __builtin_amdgcn_s_setprio(0);
  // prefetch kc0 weights for all three gates; epilogue H2 -> abuf
  wpair pi0 = wload<4>(wsp + WI_OFF, wv, 0, woff);
  wpair pg0 = wload<4>(wsp + WG_OFF, wv, 0, woff);
  wpair po0 = wload<4>(wsp + WO_OFF, wv, 0, woff);
  epi_relu(acc, abuf, fb, lane);
  __syncthreads();  // (3) H2 visible

  // ---- FUSED gate GEMMs: one abuf pass feeds i,g,o accumulators ----
  fx4 ai[4][2], ag[4][2], ao[4][2];
  zacc(ai);
  zacc(ag);
  zacc(ao);
  __builtin_amdgcn_s_setprio(1);
#pragma unroll
  for (int kc = 0; kc < 4; ++kc) {
    wpair pi = (kc == 0) ? pi0 : wload<4>(wsp + WI_OFF, wv, kc, woff);
    wpair pg = (kc == 0) ? pg0 : wload<4>(wsp + WG_OFF, wv, kc, woff);
    wpair po = (kc == 0) ? po0 : wload<4>(wsp + WO_OFF, wv, kc, woff);
    int kbyte = kc * 64 + kb0;
#pragma unroll
    for (int jt = 0; jt < 4; ++jt) {
      s16x8 a = frag_ld(abuf, jt * 16 + l15, kbyte, 8);
      ai[jt][0] = __builtin_amdgcn_mfma_f32_16x16x32_bf16(pi.w0, a, ai[jt][0], 0, 0, 0);
      ai[jt][1] = __builtin_amdgcn_mfma_f32_16x16x32_bf16(pi.w1, a, ai[jt][1], 0, 0, 0);
      ag[jt][0] = __builtin_amdgcn_mfma_f32_16x16x32_bf16(pg.w0, a, ag[jt][0], 0, 0, 0);
      ag[jt][1] = __builtin_amdgcn_mfma_f32_16x16x32_bf16(pg.w1, a, ag[jt][1], 0, 0, 0);
      ao[jt][0] = __builtin_amdgcn_mfma_f32_16x16x32_bf16(po.w0, a, ao[jt][0], 0, 0, 0);
      ao[jt][1] = __builtin_amdgcn_mfma_f32_16x16x32_bf16(po.w1, a, ao[jt][1], 0, 0, 0);
    }
  }
  __builtin_amdgcn_s_setprio(0);
  // prefetch head-weight fragments (hides under gate math)
  s16x8 hw0 = *(const s16x8*)(himg + (0 << 10) + woff);
  s16x8 hw1 = *(const s16x8*)(himg + (1 << 10) + woff);
  s16x8 hw2 = *(const s16x8*)(himg + (2 << 10) + woff);
  s16x8 hw3 = *(const s16x8*)(himg + (3 << 10) + woff);

  // ---- single gate-math pass, packed f32 pairs: h -> hbuf ----
  // h = sig(o)*tanh(sig(i)*tanh(g)); all non-trans arithmetic as fx2
  // (v_pk_fma/add/mul_f32); exp2/rcp remain scalar trans ops.
  {
    char* ob = (char*)hbuf;
#pragma unroll
    for (int it = 0; it < 2; ++it) {
      fx4 pvi = *(const fx4*)(gb + fb + it * 16 + g4);
      fx4 pvg = *(const fx4*)(gb + 128 + fb + it * 16 + g4);
      fx4 pvo = *(const fx4*)(gb + 256 + fb + it * 16 + g4);
      int n0 = fb + it * 16 + g4;
#pragma unroll
      for (int jt = 0; jt < 4; ++jt) {
        u32x2 u;
#pragma unroll
        for (int p = 0; p < 2; ++p) {
          const int r0 = 2 * p, r1 = 2 * p + 1;
          fx2 vi = mk2(ai[jt][it][r0], ai[jt][it][r1]);
          fx2 vg = mk2(ag[jt][it][r0], ag[jt][it][r1]);
          fx2 vo = mk2(ao[jt][it][r0], ao[jt][it][r1]);
          fx2 ti = vi * NEG_L + mk2(pvi[r0], pvi[r1]);  // pk_fma
          fx2 tg = vg * TWO_L + mk2(pvg[r0], pvg[r1]);
          fx2 to = vo * NEG_L + mk2(pvo[r0], pvo[r1]);
          fx2 Ei = mk2(ex2(ti[0]), ex2(ti[1]));
          fx2 Eg = mk2(ex2(tg[0]), ex2(tg[1]));
          fx2 Eo = mk2(ex2(to[0]), ex2(to[1]));
          fx2 d1 = (Eg + 1.0f) * (Ei + 1.0f);  // pk_add, pk_add, pk_mul
          fx2 r1v = mk2(frcp(d1[0]), frcp(d1[1]));
          fx2 c = (Eg - 1.0f) * r1v;           // pk_add(-1), pk_mul
          fx2 ea = c * TWO_L;                  // pk_mul
          fx2 Ec = mk2(ex2(ea[0]), ex2(ea[1]));
          fx2 d2 = (Ec + 1.0f) * (Eo + 1.0f);
          fx2 r2v = mk2(frcp(d2[0]), frcp(d2[1]));
          fx2 h2 = (Ec - 1.0f) * r2v;
          u[p] = cvtpk(h2[0], h2[1]);
        }
        int m = jt * 16 + l15;
        *(u32x2*)(ob + (m << 8) + ((n0 * 2) ^ ((m & 7) << 4))) = u;
      }
    }
  }
  __syncthreads();  // (4) h visible

  // head GEMM: wave wv -> rows wv*16..+15
  fx4 ha = fx4{0.f, 0.f, 0.f, 0.f};
  __builtin_amdgcn_s_setprio(1);
  ha = __builtin_amdgcn_mfma_f32_16x16x32_bf16(
      hw0, frag_ld(hbuf, (wv << 4) + l15, 0 + kb0, 8), ha, 0, 0, 0);
  ha = __builtin_amdgcn_mfma_f32_16x16x32_bf16(
      hw1, frag_ld(hbuf, (wv << 4) + l15, 64 + kb0, 8), ha, 0, 0, 0);
  ha = __builtin_amdgcn_mfma_f32_16x16x32_bf16(
      hw2, frag_ld(hbuf, (wv << 4) + l15, 128 + kb0, 8), ha, 0, 0, 0);
  ha = __builtin_amdgcn_mfma_f32_16x16x32_bf16(
      hw3, frag_ld(hbuf, (wv << 4) + l15, 192 + kb0, 8), ha, 0, 0, 0);
  __builtin_amdgcn_s_setprio(0);

  int m = rbase + (wv << 4) + l15;
  if (path == 0) {
    if (g4 < 8) {
      fx4 v = ha + *(const fx4*)(mb + g4);
      *(fx4*)(meanp + (size_t)m * ACTD + g4) = v;
    } else {
      fx4 v;
#pragma unroll
      for (int r = 0; r < 4; ++r) v[r] = __expf(ha[r] + lb[g4 - 8 + r]);
      *(fx4*)(stdp + (size_t)m * ACTD + (g4 - 8)) = v;
    }
  } else if (g4 == 0) {
    valp[m] = ha[0] + vb[0];
  }
}

extern "C" void kernel_launch(void* const* d_in, const int* in_sizes, int n_in,
                              void* d_out, int out_size, void* d_ws,
                              size_t ws_size, hipStream_t stream) {
  (void)in_sizes; (void)n_in; (void)ws_size; (void)out_size;
  const float* state = (const float*)d_in[0];
  const float* aw1 = (const float*)d_in[1];
  const float* ab1 = (const float*)d_in[2];
  const float* aw2 = (const float*)d_in[3];
  const float* ab2 = (const float*)d_in[4];
  const float* cw1 = (const float*)d_in[5];
  const float* cb1 = (const float*)d_in[6];
  const float* cw2 = (const float*)d_in[7];
  const float* cb2 = (const float*)d_in[8];
  const float* awih = (const float*)d_in[9];
  // d_in[10] = a_whh (unused: zero-state LSTM)
  const float* abih = (const float*)d_in[11];
  const float* abhh = (const float*)d_in[12];
  const float* cwih = (const float*)d_in[13];
  // d_in[14] = c_whh (unused)
  const float* cbih = (const float*)d_in[15];
  const float* cbhh = (const float*)d_in[16];
  const float* mw = (const float*)d_in[17];
  const float* mb = (const float*)d_in[18];
  const float* lw = (const float*)d_in[19];
  const float* lb = (const float*)d_in[20];
  const float* vw = (const float*)d_in[21];
  const float* vb = (const float*)d_in[22];
  char* ws = (char*)d_ws;

  prep_weights<<<dim3(8, 14), 256, 0, stream>>>(
      aw1, aw2, awih, cw1, cw2, cwih, mw, lw, vw, abih, abhh, cbih, cbhh, ws);
  fused_ac<<<8192, 256, 0, stream>>>(state, ab1, ab2, cb1, cb2, mb, lb, vb, ws,
                                     (float*)d_out);
}